// Round 4
// baseline (399.824 us; speedup 1.0000x reference)
//
#include <hip/hip_runtime.h>
#include <math.h>

#define NN 8192
#define FIN 128
#define FOUT 64
#define LRELU 0.2f
#define JSPLIT 32
#define JCH (NN / JSPLIT)   // 256
#define HTSTR 264           // halfs; word-stride 132 = 4 mod 32 -> balanced b128 banks
#define L2E 1.44269504f

typedef _Float16 f16x8 __attribute__((ext_vector_type(8)));
typedef float f32x4 __attribute__((ext_vector_type(4)));

// workspace layout (float offsets)
#define WS_HT 0                        // H^T as f16 [FOUT][NN] = 262144 floats
#define WS_S1 262144
#define WS_S2 270336
#define WS_S2MAX 278528
#define WS_PACC 278544                 // JSPLIT x NN x FOUT f32 partials (67 MB)
#define WS_LP (WS_PACC + JSPLIT * NN * FOUT)

// ---------------------------------------------------------------------------
// Kernel 1: h = x@W; emit s1=h@a1, s2=h@a2 (f32) and H^T (f16, [feat][row]).
// ---------------------------------------------------------------------------
__global__ __launch_bounds__(256) void k_hs(const float* __restrict__ x,
                                            const float* __restrict__ W,
                                            const float* __restrict__ a,
                                            float* ws) {
  __shared__ float Wl[FIN * FOUT];   // 32 KB
  __shared__ float xl[16 * FIN];     // 8 KB
  __shared__ float hl[16 * FOUT];    // 4 KB
  const int t = threadIdx.x;
  const int i0 = blockIdx.x * 16;

#pragma unroll
  for (int c = 0; c < 8; ++c) {
    const int flat = c * 1024 + t * 4;
    *(float4*)&Wl[flat] = *(const float4*)&W[flat];
  }
#pragma unroll
  for (int c = 0; c < 2; ++c) {
    const int flat = c * 1024 + t * 4;
    *(float4*)&xl[flat] = *(const float4*)&x[(size_t)i0 * FIN + flat];
  }
  __syncthreads();

  const int r = t >> 4;     // local row 0..15
  const int fg = t & 15;    // feat group: feats [4*fg, 4*fg+4)
  float4 acc = make_float4(0.f, 0.f, 0.f, 0.f);
#pragma unroll 4
  for (int k = 0; k < FIN; ++k) {
    const float xv = xl[r * FIN + k];
    const float4 wv = *(const float4*)&Wl[k * FOUT + fg * 4];
    acc.x = fmaf(xv, wv.x, acc.x);
    acc.y = fmaf(xv, wv.y, acc.y);
    acc.z = fmaf(xv, wv.z, acc.z);
    acc.w = fmaf(xv, wv.w, acc.w);
  }

  float v1 = acc.x * a[fg * 4] + acc.y * a[fg * 4 + 1] +
             acc.z * a[fg * 4 + 2] + acc.w * a[fg * 4 + 3];
  float v2 = acc.x * a[FOUT + fg * 4] + acc.y * a[FOUT + fg * 4 + 1] +
             acc.z * a[FOUT + fg * 4 + 2] + acc.w * a[FOUT + fg * 4 + 3];
  v1 += __shfl_xor(v1, 1); v2 += __shfl_xor(v2, 1);
  v1 += __shfl_xor(v1, 2); v2 += __shfl_xor(v2, 2);
  v1 += __shfl_xor(v1, 4); v2 += __shfl_xor(v2, 4);
  v1 += __shfl_xor(v1, 8); v2 += __shfl_xor(v2, 8);
  if (fg == 0) {
    ws[WS_S1 + i0 + r] = v1;
    ws[WS_S2 + i0 + r] = v2;
  }

  // transpose h tile -> H^T (f16) via LDS
  *(float4*)&hl[r * FOUT + fg * 4] = acc;
  __syncthreads();
  _Float16* ht = (_Float16*)(ws + WS_HT);
  if (t < 128) {
    const int f = t >> 1;
    const int off = (t & 1) * 8;
    f16x8 tmp;
#pragma unroll
    for (int u = 0; u < 8; ++u) tmp[u] = (_Float16)hl[(off + u) * FOUT + f];
    *(f16x8*)&ht[(size_t)f * NN + i0 + off] = tmp;
  }
}

// ---------------------------------------------------------------------------
// Kernel 2: S2max = max_j s2[j]  (leaky monotone -> closed-form row max)
// ---------------------------------------------------------------------------
__global__ __launch_bounds__(256) void k_s2max(float* ws) {
  __shared__ float red[256];
  const int t = threadIdx.x;
  float v = -1e30f;
#pragma unroll
  for (int i = 0; i < NN / 256; ++i) v = fmaxf(v, ws[WS_S2 + i * 256 + t]);
  red[t] = v;
  __syncthreads();
  for (int s = 128; s >= 1; s >>= 1) {
    if (t < s) red[t] = fmaxf(red[t], red[t + s]);
    __syncthreads();
  }
  if (t == 0) ws[WS_S2MAX] = red[0];
}

// ---------------------------------------------------------------------------
// Kernel 3: barrier-free streaming pass, occupancy-tuned.
// Grid: 128 i-blocks x 32 j-splits = 4096 blocks, 256 thr (4 waves).
// LDS = 33.8 KB H^T tile + 1 KB s2 -> 4 blocks/CU = 16 waves/CU.
// Lane computes its MFMA A-frag p-values in registers from its own adj
// loads (A[m=l&15][k=q*8+u]); j-loop (8 iters) has NO barriers.
// ---------------------------------------------------------------------------
__global__ __launch_bounds__(256, 4) void k_main(const int* __restrict__ adj,
                                                 float* ws) {
  __shared__ __align__(16) _Float16 htl[FOUT * HTSTR];  // 33792 B
  __shared__ float s2l[JCH];                            // 1 KB

  const int t = threadIdx.x;
  const int ib = blockIdx.x >> 5;
  const int js = blockIdx.x & 31;
  const int i0 = ib * 64;
  const int jc0 = js * JCH;

  const _Float16* ht = (const _Float16*)(ws + WS_HT);

  // stage H^T chunk: 64 feats x 256 halfs, coalesced 16B
#pragma unroll
  for (int c = 0; c < 8; ++c) {
    const int chunk = c * 256 + t;      // 0..2047
    const int f = chunk >> 5;
    const int off = (chunk & 31) * 8;
    *(f16x8*)&htl[f * HTSTR + off] = *(const f16x8*)&ht[(size_t)f * NN + jc0 + off];
  }
  s2l[t] = ws[WS_S2 + jc0 + t];   // JCH == blockDim == 256

  const int w = t >> 6;     // wave 0..3
  const int l = t & 63;
  const int m16 = l & 15;
  const int q8 = (l >> 4) * 8;
  const int row = i0 + w * 16 + m16;

  const float s2max = ws[WS_S2MAX];
  const float s1v = ws[WS_S1 + row];
  const float tmp0 = s1v + s2max;
  const float mv = fmaxf(tmp0, LRELU * tmp0);
  const float mneg = -mv * L2E;

  f32x4 acc[4];
#pragma unroll
  for (int nf = 0; nf < 4; ++nf) acc[nf] = (f32x4){0.f, 0.f, 0.f, 0.f};
  float lacc = 0.f;

  const int* arow = adj + (size_t)row * NN + jc0 + q8;

  __syncthreads();   // the only barrier

#pragma unroll 4
  for (int it = 0; it < JCH / 32; ++it) {   // 8 iterations
    const int4 a0 = *(const int4*)(arow + it * 32);
    const int4 a1 = *(const int4*)(arow + it * 32 + 4);
    const float4 s20 = *(const float4*)&s2l[it * 32 + q8];
    const float4 s21 = *(const float4*)&s2l[it * 32 + q8 + 4];

    float e, p[8];
    e = s1v + s20.x; e = fmaxf(e, LRELU * e); p[0] = a0.x ? exp2f(fmaf(e, L2E, mneg)) : 0.f;
    e = s1v + s20.y; e = fmaxf(e, LRELU * e); p[1] = a0.y ? exp2f(fmaf(e, L2E, mneg)) : 0.f;
    e = s1v + s20.z; e = fmaxf(e, LRELU * e); p[2] = a0.z ? exp2f(fmaf(e, L2E, mneg)) : 0.f;
    e = s1v + s20.w; e = fmaxf(e, LRELU * e); p[3] = a0.w ? exp2f(fmaf(e, L2E, mneg)) : 0.f;
    e = s1v + s21.x; e = fmaxf(e, LRELU * e); p[4] = a1.x ? exp2f(fmaf(e, L2E, mneg)) : 0.f;
    e = s1v + s21.y; e = fmaxf(e, LRELU * e); p[5] = a1.y ? exp2f(fmaf(e, L2E, mneg)) : 0.f;
    e = s1v + s21.z; e = fmaxf(e, LRELU * e); p[6] = a1.z ? exp2f(fmaf(e, L2E, mneg)) : 0.f;
    e = s1v + s21.w; e = fmaxf(e, LRELU * e); p[7] = a1.w ? exp2f(fmaf(e, L2E, mneg)) : 0.f;

    f16x8 af;
#pragma unroll
    for (int u = 0; u < 8; ++u) af[u] = (_Float16)p[u];
    // denominator from the f16-rounded p: cancels rounding in the ratio
#pragma unroll
    for (int u = 0; u < 8; ++u) lacc += (float)af[u];

    const int kb = it * 32 + q8;
#pragma unroll
    for (int nf = 0; nf < 4; ++nf) {
      const f16x8 b = *(const f16x8*)&htl[(nf * 16 + m16) * HTSTR + kb];
      acc[nf] = __builtin_amdgcn_mfma_f32_16x16x32_f16(af, b, acc[nf], 0, 0, 0);
    }
  }

  // row-sum partial: reduce lacc across the 4 quads (same m16)
  lacc += __shfl_xor(lacc, 16);
  lacc += __shfl_xor(lacc, 32);
  if (l < 16) ws[WS_LP + js * NN + row] = lacc;

  // acc partials: C/D layout col=lane&15, row=(lane>>4)*4+reg
  float* pacc = ws + WS_PACC + (size_t)js * (NN * FOUT);
  const int orow = i0 + w * 16 + (l >> 4) * 4;
  const int ocol = m16;
#pragma unroll
  for (int nf = 0; nf < 4; ++nf)
#pragma unroll
    for (int r = 0; r < 4; ++r)
      pacc[(size_t)(orow + r) * FOUT + nf * 16 + ocol] = acc[nf][r];
}

// ---------------------------------------------------------------------------
// Kernel 4: combine j-split partials, normalize, ELU
// ---------------------------------------------------------------------------
__global__ __launch_bounds__(256) void k_combine(const float* __restrict__ ws,
                                                 float* __restrict__ out) {
  const int idx = blockIdx.x * 256 + threadIdx.x;
  const int i = idx >> 6;
  float s = 0.f, l = 0.f;
#pragma unroll
  for (int js = 0; js < JSPLIT; ++js) {
    s += ws[WS_PACC + (size_t)js * (NN * FOUT) + idx];
    l += ws[WS_LP + js * NN + i];
  }
  const float v = s / l;
  out[idx] = v > 0.f ? v : expm1f(v);
}

// ---------------------------------------------------------------------------
extern "C" void kernel_launch(void* const* d_in, const int* in_sizes, int n_in,
                              void* d_out, int out_size, void* d_ws,
                              size_t ws_size, hipStream_t stream) {
  const float* x = (const float*)d_in[0];
  const int* adj = (const int*)d_in[1];
  const float* W = (const float*)d_in[2];
  const float* a = (const float*)d_in[3];
  float* ws = (float*)d_ws;
  float* out = (float*)d_out;

  hipLaunchKernelGGL(k_hs, dim3(NN / 16), dim3(256), 0, stream, x, W, a, ws);
  hipLaunchKernelGGL(k_s2max, dim3(1), dim3(256), 0, stream, ws);
  hipLaunchKernelGGL(k_main, dim3((NN / 64) * JSPLIT), dim3(256), 0, stream,
                     adj, ws);
  hipLaunchKernelGGL(k_combine, dim3(NN * FOUT / 256), dim3(256), 0, stream,
                     ws, out);
}